// Round 6
// baseline (171.397 us; speedup 1.0000x reference)
//
#include <hip/hip_runtime.h>

// NeuSSampler PDF importance resampling — persistent waves, grid-stride,
// register double-buffered prefetch, segment-parallel compute (round-3 body).
//
// 2048 blocks x 256 threads = 8192 waves, fully resident on 256 CUs
// (8 waves/SIMD). Each wave grid-strides over rays (131072/8192 = 16 per
// wave). Loop body: issue ray n+1's global loads (independent registers, no
// wait), then compute ray n from registers already in hand. Steady state
// hides the ~900-cycle HBM latency under compute; waves never relaunch, so
// the per-generation load convoy of the block-per-ray versions disappears.
//
// Compute per ray (no LDS, no __syncthreads): lane l owns weight/bin pair
// (2l, 2l+1); pair-sum DPP inclusive scan -> cdf edges in registers.
// Queries u_j=(2j+1)/130 are an arithmetic progression: segment k covers
// exactly j in [jf(cdf[k]), jf(cdf[k+1])), jf(c)=ceil(65c-0.5). Shared
// edges are bit-identical across lanes (shuffled), so ranges tile [0,65)
// exactly. Per segment: one v_rcp, incremental t — no division in loops.
// Degenerates: duplicate cdf -> empty range; forced lane-63 range with d=0
// -> t=inf/NaN -> clamp(NaN)=0 / clip(inf)=1 reproduces nan_to_num+clip.

#define DPP_FADD(x, ctrl, rmask)                                             \
    ((x) + __int_as_float(__builtin_amdgcn_update_dpp(                       \
               0, __float_as_int(x), (ctrl), (rmask), 0xf, true)))

__global__ __launch_bounds__(256) void neus_sampler_kernel(
    const float* __restrict__ weights,
    const float* __restrict__ bins_g,
    const float* __restrict__ nears,
    const float* __restrict__ fars,
    float* __restrict__ out,
    int R)
{
    constexpr int S  = 128;   // weights per ray
    constexpr int SE = 129;   // bin edges per ray
    constexpr int NB = 65;    // output samples per ray
    constexpr float HPAD = 1e-5f;

    const int lane = threadIdx.x & 63;
    const int gw   = blockIdx.x * 4 + (threadIdx.x >> 6);  // global wave id
    const int nw   = gridDim.x * 4;                        // total waves

    // first query index j with u_j >= c  (u_j = (2j+1)/130)
    auto jf = [](float c) -> int {
        int j = (int)ceilf(fmaf(65.0f, c, -0.5f));
        return j < 0 ? 0 : (j > NB ? NB : j);
    };

    float2 W, Bp;                 // current ray's weight/bin pair
    float  BL, NE, FA;            // bins[128], near, far (wave-uniform)

    int ray = gw;
    if (ray < R) {                // prologue: load ray 0's inputs
        const int ur = __builtin_amdgcn_readfirstlane(ray);
        W = reinterpret_cast<const float2*>(weights + (size_t)ur * S)[lane];
        const float* brow = bins_g + (size_t)ur * SE;
        Bp = reinterpret_cast<const float2*>(brow)[lane];
        BL = brow[S]; NE = nears[ur]; FA = fars[ur];
    }

    while (ray < R) {
        // ---- issue next ray's loads (no dependence on current compute) ----
        const int nray = ray + nw;
        float2 W2, B2; float BL2, NE2, FA2;
        if (nray < R) {           // wave-uniform branch
            const int ur2 = __builtin_amdgcn_readfirstlane(nray);
            W2 = reinterpret_cast<const float2*>(weights + (size_t)ur2 * S)[lane];
            const float* brow2 = bins_g + (size_t)ur2 * SE;
            B2 = reinterpret_cast<const float2*>(brow2)[lane];
            BL2 = brow2[S]; NE2 = nears[ur2]; FA2 = fars[ur2];
        }

        // ---- compute current ray from resident registers ----
        const int ur = __builtin_amdgcn_readfirstlane(ray);
        const float w1 = W.y + HPAD;
        float ps = (W.x + HPAD) + w1;            // pair sum
        ps = DPP_FADD(ps, 0x111, 0xf);  // row_shr:1
        ps = DPP_FADD(ps, 0x112, 0xf);  // row_shr:2
        ps = DPP_FADD(ps, 0x114, 0xf);  // row_shr:4
        ps = DPP_FADD(ps, 0x118, 0xf);  // row_shr:8
        ps = DPP_FADD(ps, 0x142, 0xa);  // row_bcast:15 -> rows 1,3
        ps = DPP_FADD(ps, 0x143, 0xc);  // row_bcast:31 -> rows 2,3

        const float total = __int_as_float(
            __builtin_amdgcn_readlane(__float_as_int(ps), 63));
        const float padding = fmaxf(1e-5f - total, 0.0f);  // relu(EPS - sum)
        const float padc    = padding * (1.0f / S);
        const float inv     = __builtin_amdgcn_rcpf(total + padding);

        const float c_hi  = fminf(1.0f, fmaf((float)(2*lane+2), padc, ps) * inv);
        const float c_mid = fminf(1.0f, fmaf((float)(2*lane+1), padc, ps - w1) * inv);
        float c_lo = __shfl_up(c_hi, 1, 64);
        if (lane == 0) c_lo = 0.0f;              // cdf[0]
        float b2 = __shfl_down(Bp.x, 1, 64);     // bins[2l+2]
        if (lane == 63) b2 = BL;                 // bins[128]

        const int j0 = jf(c_lo);
        const int j2 = (lane == 63) ? NB : jf(c_hi);
        int j1 = jf(c_mid);
        j1 = j1 < j0 ? j0 : (j1 > j2 ? j2 : j1); // tile [j0,j2) exactly

        const float fmn = FA - NE;
        float* orow = out + (size_t)ur * NB;

        if (j1 > j0) {                           // segment [c_lo, c_mid)
            const float r  = __builtin_amdgcn_rcpf(c_mid - c_lo);
            const float dt = r * (1.0f / 65.0f);
            const float bd = Bp.y - Bp.x;
            float t = fmaf((float)(2*j0+1), (1.0f/130.0f), -c_lo) * r;
            for (int j = j0; j < j1; ++j) {
                const float tc = fminf(fmaxf(t, 0.0f), 1.0f);
                orow[j] = fmaf(fmaf(tc, bd, Bp.x), fmn, NE);
                t += dt;
            }
        }
        if (j2 > j1) {                           // segment [c_mid, c_hi)
            const float r  = __builtin_amdgcn_rcpf(c_hi - c_mid);  // inf ok
            const float dt = r * (1.0f / 65.0f);
            const float bd = b2 - Bp.y;
            float t = fmaf((float)(2*j1+1), (1.0f/130.0f), -c_mid) * r;
            for (int j = j1; j < j2; ++j) {
                const float tc = fminf(fmaxf(t, 0.0f), 1.0f);  // NaN-safe ->0
                orow[j] = fmaf(fmaf(tc, bd, Bp.y), fmn, NE);
                t += dt;
            }
        }

        // ---- rotate prefetched registers ----
        ray = nray;
        W = W2; Bp = B2; BL = BL2; NE = NE2; FA = FA2;
    }
}

extern "C" void kernel_launch(void* const* d_in, const int* in_sizes, int n_in,
                              void* d_out, int out_size, void* d_ws, size_t ws_size,
                              hipStream_t stream) {
    const float* weights = (const float*)d_in[0];   // [R,128,1]
    const float* ebins   = (const float*)d_in[1];   // [R,129]
    const float* nears   = (const float*)d_in[2];   // [R,1]
    const float* fars    = (const float*)d_in[3];   // [R,1]
    float* out = (float*)d_out;                     // [R,65]
    const int R = in_sizes[0] / 128;
    // Persistent grid: 2048 blocks x 4 waves = 8192 waves — exactly fills
    // 256 CUs at 8 waves/SIMD; each wave grid-strides (R/8192 = 16 rays).
    const int blocks = 2048;
    hipLaunchKernelGGL(neus_sampler_kernel, dim3(blocks), dim3(256), 0, stream,
                       weights, ebins, nears, fars, out, R);
}